// Round 5
// baseline (1298.060 us; speedup 1.0000x reference)
//
#include <hip/hip_runtime.h>
#include <hip/hip_bf16.h>
#include <float.h>

// Problem constants
#define BB   128      // bs*t
#define CCH  256      // z channels
#define EMB_ 256      // embedding dim
#define HW   256      // h*w
#define NPIX 32768    // BB*HW
#define VOC  4096

#define PCAP   96         // candidate list capacity per pixel
#define MARGIN 4e-5f      // screen margin (>= 2*(eps_screen+eps_grid) ~ 1.7e-5)

typedef __attribute__((ext_vector_type(8))) short bf16x8;
typedef __attribute__((ext_vector_type(4))) float f32x4;
typedef unsigned short ushort_t;
typedef unsigned int   uint_t;

// bf16 round-to-nearest-even split helpers (device)
__device__ __forceinline__ ushort_t bf16_rne(float v) {
    uint_t b = __float_as_uint(v);
    return (ushort_t)((b + 0x7FFFu + ((b >> 16) & 1u)) >> 16);
}
__device__ __forceinline__ float bf16_tof(ushort_t h) {
    return __uint_as_float((uint_t)h << 16);
}

// ---------------------------------------------------------------- K0a: c_sq
__global__ __launch_bounds__(256) void k_csq(const float* __restrict__ cb,
                                             float* __restrict__ csq) {
    int v = blockIdx.x * 256 + threadIdx.x;   // grid 16
    const float4* row = (const float4*)(cb + v * EMB_);
    float s = 0.f;
#pragma unroll 8
    for (int q = 0; q < 64; ++q) {
        float4 a = row[q];
        s = fmaf(a.x, a.x, fmaf(a.y, a.y, fmaf(a.z, a.z, fmaf(a.w, a.w, s))));
    }
    csq[v] = s;
}

// ------------------------------------------- K0b: postcode = post_b + W@cb^T
__global__ __launch_bounds__(256) void k_postcode(const float* __restrict__ cb,
                                                  const float* __restrict__ post_w,
                                                  const float* __restrict__ post_b,
                                                  float* __restrict__ postcode) {
    __shared__ float cbs[16][EMB_];           // 16 codebook rows, 16 KB
    int v0 = blockIdx.x * 16;                 // grid 256
    int c  = threadIdx.x;
#pragma unroll
    for (int r = 0; r < 16; ++r)
        cbs[r][c] = cb[(v0 + r) * EMB_ + c];  // coalesced
    __syncthreads();

    float acc[16];
    float bias = post_b[c];
#pragma unroll
    for (int r = 0; r < 16; ++r) acc[r] = bias;

    const float4* w4p = (const float4*)(post_w + c * EMB_);
    for (int e4 = 0; e4 < 64; ++e4) {
        float4 w4 = w4p[e4];
#pragma unroll
        for (int r = 0; r < 16; ++r) {
            float4 c4 = *(const float4*)&cbs[r][e4 * 4];
            acc[r] = fmaf(w4.x, c4.x, fmaf(w4.y, c4.y,
                     fmaf(w4.z, c4.z, fmaf(w4.w, c4.w, acc[r]))));
        }
    }
#pragma unroll
    for (int r = 0; r < 16; ++r)
        postcode[(v0 + r) * CCH + c] = acc[r];  // coalesced
}

// ---------------------------- K0c: codebook bf16 hi/lo split (cbh, cbl)
__global__ __launch_bounds__(256) void k_cbsplit(const float* __restrict__ cb,
                                                 ushort_t* __restrict__ cbh,
                                                 ushort_t* __restrict__ cbl) {
    int idx = blockIdx.x * 256 + threadIdx.x;   // grid 4096 -> 1,048,576
    float v = cb[idx];
    ushort_t h = bf16_rne(v);
    float lo = v - bf16_tof(h);
    cbh[idx] = h;
    cbl[idx] = bf16_rne(lo);
}

// ---------------------------------------------------- K1: pre-conv -> z_out
__global__ __launch_bounds__(256) void k_preconv(const float* __restrict__ x,
                                                 const float* __restrict__ pre_w,
                                                 const float* __restrict__ pre_b,
                                                 float* __restrict__ zout) {
    __shared__ float xsT[16][260];            // [p][c], +4 pad kills conflicts
    int b   = blockIdx.x >> 4;                // grid 2048
    int hw0 = (blockIdx.x & 15) * 16;
    int tid = threadIdx.x;
    int cg = tid >> 4, p = tid & 15;
#pragma unroll
    for (int it = 0; it < 16; ++it) {
        int c = it * 16 + cg;
        xsT[p][c] = 2.f * x[b * (CCH * HW) + c * HW + hw0 + p] - 1.f;
    }
    __syncthreads();

    int e = tid;
    float acc[16];
    float bias = pre_b[e];
#pragma unroll
    for (int q = 0; q < 16; ++q) acc[q] = bias;

    const float4* w4p = (const float4*)(pre_w + e * CCH);
    for (int c4 = 0; c4 < 64; ++c4) {
        float4 w4 = w4p[c4];
#pragma unroll
        for (int q = 0; q < 16; ++q) {
            float4 xv = *(const float4*)&xsT[q][c4 * 4];
            acc[q] = fmaf(w4.x, xv.x, fmaf(w4.y, xv.y,
                     fmaf(w4.z, xv.z, fmaf(w4.w, xv.w, acc[q]))));
        }
    }
    float* zo = zout + b * (EMB_ * HW) + e * HW + hw0;
#pragma unroll
    for (int q = 0; q < 4; ++q) {
        float4 s;
        s.x = acc[q * 4 + 0]; s.y = acc[q * 4 + 1];
        s.z = acc[q * 4 + 2]; s.w = acc[q * 4 + 3];
        *(float4*)&zo[q * 4] = s;
    }
}

// -------------------- K1b: z transpose + bf16 hi/lo split + exact zsq chain
// zbh/zbl: [pix][256] bf16, pix = b*256 + hw.  zsq: serial fmaf chain e=0..255
// (bit-identical to the chain used by the passing R1-R4 kernels).
__global__ __launch_bounds__(256) void k_split(const float* __restrict__ zout,
                                               ushort_t* __restrict__ zbh,
                                               ushort_t* __restrict__ zbl,
                                               float* __restrict__ zsq) {
    __shared__ float ts[32][260];
    int b = blockIdx.x;                        // grid 128
    int t = threadIdx.x;                       // = hw
    const float* zb = zout + (size_t)b * 65536;
    size_t rowo = (size_t)(b * 256 + t) * 256;
    float zacc = 0.f;
    for (int tile = 0; tile < 8; ++tile) {
        int e0 = tile * 32;
        __syncthreads();
#pragma unroll
        for (int i = 0; i < 32; ++i)
            ts[i][t] = zb[(size_t)(e0 + i) * 256 + t];   // coalesced
        __syncthreads();
        // exact serial zsq chain, ascending e
#pragma unroll
        for (int i = 0; i < 32; ++i) { float v = ts[i][t]; zacc = fmaf(v, v, zacc); }
        // split + transposed write (16B per store)
#pragma unroll
        for (int g = 0; g < 4; ++g) {
            uint_t hv[4], lv[4];
#pragma unroll
            for (int u = 0; u < 4; ++u) {
                int i = g * 8 + u * 2;
                float v0 = ts[i][t], v1 = ts[i + 1][t];
                ushort_t h0 = bf16_rne(v0);
                ushort_t l0 = bf16_rne(v0 - bf16_tof(h0));
                ushort_t h1 = bf16_rne(v1);
                ushort_t l1 = bf16_rne(v1 - bf16_tof(h1));
                hv[u] = (uint_t)h0 | ((uint_t)h1 << 16);
                lv[u] = (uint_t)l0 | ((uint_t)l1 << 16);
            }
            *(uint4*)(zbh + rowo + e0 + g * 8) = make_uint4(hv[0], hv[1], hv[2], hv[3]);
            *(uint4*)(zbl + rowo + e0 + g * 8) = make_uint4(lv[0], lv[1], lv[2], lv[3]);
        }
    }
    zsq[b * 256 + t] = zacc;
}

// ------------------- K2a: MFMA screen + margin candidate emission
// Screen score = csq[v] - 2*(zh.ch + zh.cl + zl.ch) + 1.0 (bias keeps >0 for
// uint atomicMin). Every code within MARGIN of the running per-pixel best is
// emitted; the true argmin provably always emits. Tokens decided by rescore.
// Block = 64 pixels; wave w: pixel-half hp=w&1 (2 16-px A tiles), code-half
// hc=w>>1 (4 16-code B subtiles per 128-code chunk). z-hi resident in LDS;
// z-lo and codebook hi/lo streamed from L2 (per-lane 16B b128 frags).
#define MSTEP(T, S) \
    A##T##S = __builtin_amdgcn_mfma_f32_16x16x32_bf16(al##T, bh##S, A##T##S, 0, 0, 0); \
    A##T##S = __builtin_amdgcn_mfma_f32_16x16x32_bf16(ah##T, bl##S, A##T##S, 0, 0, 0); \
    A##T##S = __builtin_amdgcn_mfma_f32_16x16x32_bf16(ah##T, bh##S, A##T##S, 0, 0, 0);

#define EMIT1(D, PL, V) { \
    float pb = __uint_as_float(pbest[PL]); \
    if ((D) < pb + MARGIN) { \
        uint_t slot = atomicAdd(&cnt_s[PL], 1u); \
        if (slot < PCAP) lists_s[(PL) * PCAP + slot] = (uint_t)(V); \
        if ((D) < pb) atomicMin(&pbest[PL], __float_as_uint(D)); \
    } }

#define FOLD_TS(T, S) { \
    int vcode = cb0 + 16 * (S); \
    float basev = csq[vcode] + 1.0f; \
    int plb = 32 * hp + 16 * (T) + 4 * q; \
    float d0 = fmaf(-2.0f, A##T##S[0], basev); EMIT1(d0, plb + 0, vcode) \
    float d1 = fmaf(-2.0f, A##T##S[1], basev); EMIT1(d1, plb + 1, vcode) \
    float d2 = fmaf(-2.0f, A##T##S[2], basev); EMIT1(d2, plb + 2, vcode) \
    float d3 = fmaf(-2.0f, A##T##S[3], basev); EMIT1(d3, plb + 3, vcode) }

__global__ __launch_bounds__(256) void k_screen(const ushort_t* __restrict__ zbh,
                                                const ushort_t* __restrict__ zbl,
                                                const ushort_t* __restrict__ cbh,
                                                const ushort_t* __restrict__ cbl,
                                                const float* __restrict__ csq,
                                                uint_t* __restrict__ cnt_g,
                                                uint_t* __restrict__ list_g) {
    __shared__ ushort_t zsh[64 * 264];        // z-hi [px][k], +8 pad: 33792 B
    __shared__ uint_t   lists_s[64 * PCAP];   // 24576 B
    __shared__ uint_t   pbest[64];
    __shared__ uint_t   cnt_s[64];

    int px0 = blockIdx.x * 64;                // grid 512
    int tid = threadIdx.x;

    // load z-hi tile: 64 rows x 512 B
    {
        int r = tid >> 2, seg = tid & 3;
        const ushort_t* src = zbh + (size_t)(px0 + r) * 256 + seg * 64;
        int dst = r * 264 + seg * 64;
#pragma unroll
        for (int i = 0; i < 8; ++i)
            *(uint4*)&zsh[dst + i * 8] = *(const uint4*)(src + i * 8);
    }
    if (tid < 64) { pbest[tid] = __float_as_uint(1e30f); cnt_s[tid] = 0u; }
    __syncthreads();

    int w  = tid >> 6;
    int L  = tid & 63;
    int m  = L & 15;
    int q  = L >> 4;
    int hp = w & 1;
    int hc = w >> 1;

    int offA0 = (32 * hp + m) * 264 + 8 * q;
    int offA1 = offA0 + 16 * 264;
    const ushort_t* pal0 = zbl + (size_t)(px0 + 32 * hp + m) * 256 + 8 * q;
    const ushort_t* pal1 = pal0 + 16 * 256;

    for (int chunk = 0; chunk < 32; ++chunk) {
        __syncthreads();                      // lockstep for L1 reuse of B
        int cb0 = chunk * 128 + 64 * hc + m;
        const ushort_t* pbh0 = cbh + (size_t)cb0 * 256 + 8 * q;
        const ushort_t* pbh1 = pbh0 + 16 * 256;
        const ushort_t* pbh2 = pbh0 + 32 * 256;
        const ushort_t* pbh3 = pbh0 + 48 * 256;
        const ushort_t* pbl0 = cbl + (size_t)cb0 * 256 + 8 * q;
        const ushort_t* pbl1 = pbl0 + 16 * 256;
        const ushort_t* pbl2 = pbl0 + 32 * 256;
        const ushort_t* pbl3 = pbl0 + 48 * 256;

        f32x4 A00 = {0.f,0.f,0.f,0.f}, A01 = A00, A02 = A00, A03 = A00;
        f32x4 A10 = A00, A11 = A00, A12 = A00, A13 = A00;

#pragma unroll
        for (int ks = 0; ks < 8; ++ks) {
            bf16x8 ah0 = *(const bf16x8*)&zsh[offA0 + 32 * ks];
            bf16x8 ah1 = *(const bf16x8*)&zsh[offA1 + 32 * ks];
            bf16x8 al0 = *(const bf16x8*)(pal0 + 32 * ks);
            bf16x8 al1 = *(const bf16x8*)(pal1 + 32 * ks);
            bf16x8 bh0 = *(const bf16x8*)(pbh0 + 32 * ks);
            bf16x8 bh1 = *(const bf16x8*)(pbh1 + 32 * ks);
            bf16x8 bh2 = *(const bf16x8*)(pbh2 + 32 * ks);
            bf16x8 bh3 = *(const bf16x8*)(pbh3 + 32 * ks);
            bf16x8 bl0 = *(const bf16x8*)(pbl0 + 32 * ks);
            bf16x8 bl1 = *(const bf16x8*)(pbl1 + 32 * ks);
            bf16x8 bl2 = *(const bf16x8*)(pbl2 + 32 * ks);
            bf16x8 bl3 = *(const bf16x8*)(pbl3 + 32 * ks);
            MSTEP(0,0) MSTEP(0,1) MSTEP(0,2) MSTEP(0,3)
            MSTEP(1,0) MSTEP(1,1) MSTEP(1,2) MSTEP(1,3)
        }
        FOLD_TS(0,0) FOLD_TS(0,1) FOLD_TS(0,2) FOLD_TS(0,3)
        FOLD_TS(1,0) FOLD_TS(1,1) FOLD_TS(1,2) FOLD_TS(1,3)
    }
    __syncthreads();
    // dump lists + raw counts (count > PCAP signals rescore full-scan)
    for (int i = tid; i < 64 * PCAP; i += 256)
        list_g[(size_t)px0 * PCAP + i] = lists_s[i];
    if (tid < 64) cnt_g[px0 + tid] = cnt_s[tid];
}

// ------------------- K2b: exact fp32 rescore of candidates -> tokens
// Byte-identical arithmetic to the passing R1-R4 kernels: serial fmaf dot
// ascending e, d = (zsq + csq) - 2*acc, first-index tie-break.
__global__ __launch_bounds__(128) void k_rescore(const float* __restrict__ zout,
                                                 const float* __restrict__ cb,
                                                 const float* __restrict__ csq,
                                                 const float* __restrict__ zsq,
                                                 const uint_t* __restrict__ cnt_g,
                                                 const uint_t* __restrict__ list_g,
                                                 float* __restrict__ tok_f) {
    int pix = blockIdx.x * 128 + threadIdx.x;   // grid 256
    int b = pix >> 8, hw = pix & 255;
    const float* zp = zout + (size_t)b * 65536 + hw;   // stride 256 per e
    float zs = zsq[pix];
    uint_t n = cnt_g[pix];
    float bestd = FLT_MAX; int bi = VOC;
    if (n == 0u || n > (uint_t)PCAP) {
        // overflow fallback: exact scan of all codes
        for (int v = 0; v < VOC; ++v) {
            const float* cr = cb + (size_t)v * 256;
            float acc = 0.f;
#pragma unroll 8
            for (int e = 0; e < 256; ++e) acc = fmaf(zp[(size_t)e * 256], cr[e], acc);
            float d = (zs + csq[v]) - 2.0f * acc;
            if (d < bestd || (d == bestd && v < bi)) { bestd = d; bi = v; }
        }
    } else {
        const uint_t* lst = list_g + (size_t)pix * PCAP;
        for (uint_t c = 0; c < n; ++c) {
            int v = (int)lst[c];
            const float* cr = cb + (size_t)v * 256;
            float acc = 0.f;
#pragma unroll 8
            for (int e = 0; e < 256; ++e) acc = fmaf(zp[(size_t)e * 256], cr[e], acc);
            float d = (zs + csq[v]) - 2.0f * acc;
            if (d < bestd || (d == bestd && v < bi)) { bestd = d; bi = v; }
        }
    }
    tok_f[pix] = (float)bi;
}

// ------------------------- K3: gather zq_out = cb[t], recon = postcode[t]
__global__ __launch_bounds__(256) void k_gather(const float* __restrict__ tok_f,
                                                const float* __restrict__ cb,
                                                const float* __restrict__ postcode,
                                                float* __restrict__ zq_out,
                                                float* __restrict__ recon) {
    int b  = blockIdx.x >> 3;                 // grid 1024
    int e0 = (blockIdx.x & 7) * 32;
    int hw = threadIdx.x;
    int t  = (int)tok_f[b * HW + hw];
    const float* cbr = cb       + t * EMB_;
    const float* pcr = postcode + t * CCH;
    float* zq = zq_out + b * (EMB_ * HW) + hw;
    float* rc = recon  + b * (CCH * HW) + hw;
#pragma unroll
    for (int j = 0; j < 32; ++j) {
        int e = e0 + j;
        zq[e * HW] = cbr[e];                  // stores coalesced across hw
        rc[e * HW] = pcr[e];
    }
}

extern "C" void kernel_launch(void* const* d_in, const int* in_sizes, int n_in,
                              void* d_out, int out_size, void* d_ws, size_t ws_size,
                              hipStream_t stream) {
    const float* x      = (const float*)d_in[0];
    const float* cb     = (const float*)d_in[1];
    const float* pre_w  = (const float*)d_in[2];
    const float* pre_b  = (const float*)d_in[3];
    const float* post_w = (const float*)d_in[4];
    const float* post_b = (const float*)d_in[5];

    float* out    = (float*)d_out;
    float* z_out  = out;                       //  8388608 elems
    float* zq_out = out + 8388608;             //  8388608
    float* recon  = out + 16777216;            //  8388608
    float* tok_f  = out + 25165824;            //    32768

    // ws: small persistent scratch (same footprint as R1-R4)
    float* csq      = (float*)d_ws;            // 4096
    float* postcode = csq + VOC;               // 1,048,576
    float* zsq      = postcode + VOC * CCH;    // 32768

    // large scratch lives in the zq_out/recon region (overwritten by k_gather
    // at the end; harness re-poisons it anyway)
    float* scr = zq_out;                                  // 16,777,216 floats
    ushort_t* zbh    = (ushort_t*)scr;                    // 8.4M u16
    ushort_t* zbl    = (ushort_t*)(scr + 4194304);        // 8.4M u16
    uint_t*   list_g = (uint_t*)(scr + 8388608);          // 32768*96 u32
    uint_t*   cnt_g  = (uint_t*)(scr + 11534336);         // 32768 u32
    ushort_t* cbh    = (ushort_t*)(scr + 11567104);       // 1.05M u16
    ushort_t* cbl    = (ushort_t*)(scr + 12091392);       // 1.05M u16

    k_csq     <<<  16, 256, 0, stream>>>(cb, csq);
    k_postcode<<< 256, 256, 0, stream>>>(cb, post_w, post_b, postcode);
    k_cbsplit <<<4096, 256, 0, stream>>>(cb, cbh, cbl);
    k_preconv <<<2048, 256, 0, stream>>>(x, pre_w, pre_b, z_out);
    k_split   <<< 128, 256, 0, stream>>>(z_out, zbh, zbl, zsq);
    k_screen  <<< 512, 256, 0, stream>>>(zbh, zbl, cbh, cbl, csq, cnt_g, list_g);
    k_rescore <<< 256, 128, 0, stream>>>(z_out, cb, csq, zsq, cnt_g, list_g, tok_f);
    k_gather  <<<1024, 256, 0, stream>>>(tok_f, cb, postcode, zq_out, recon);
}